// Round 1
// baseline (252.995 us; speedup 1.0000x reference)
//
#include <hip/hip_runtime.h>
#include <hip/hip_bf16.h>

typedef unsigned short ushort_t;
typedef __attribute__((ext_vector_type(8))) __bf16 bf16x8;
typedef __attribute__((ext_vector_type(4))) float f32x4;
typedef __attribute__((ext_vector_type(2))) unsigned int u32x2;
typedef __attribute__((ext_vector_type(8))) unsigned short us8;

#define DEV __device__ __forceinline__

constexpr int BB = 2, EE = 1024, SS = 2048, HH = 16;
constexpr float L2E = 1.44269504088896f;
constexpr float SCALE_Q = 0.125f * 1.44269504088896f; // dh^-0.5 * log2(e) folded

DEV ushort_t f2bf(float x) {
  union { float f; unsigned u; } c; c.f = x;
  unsigned u = c.u;
  return (ushort_t)((u + 0x7fffu + ((u >> 16) & 1u)) >> 16); // RNE
}

DEV void gload16(const void* g, void* l) {
  __builtin_amdgcn_global_load_lds((const __attribute__((address_space(1))) void*)g,
                                   (__attribute__((address_space(3))) void*)l, 16, 0, 0);
}

// ---------------- prep: transpose + f32->bf16 (q,k,v -> [b][s][e]) ----------------
struct TpArgs { const float* i0; const float* i1; const float* i2;
                ushort_t* o0; ushort_t* o1; ushort_t* o2; };

__global__ __launch_bounds__(256) void k_transpose_cvt(TpArgs a) {
  int z = blockIdx.z; int p = z >> 1; int b = z & 1;
  const float* in = (p == 0) ? a.i0 : (p == 1) ? a.i1 : a.i2;
  ushort_t* out = (p == 0) ? a.o0 : (p == 1) ? a.o1 : a.o2;
  in += (long long)b * EE * SS;
  out += (long long)b * SS * EE;
  int s0 = blockIdx.x * 64, e0 = blockIdx.y * 64;
  __shared__ __align__(16) ushort_t T[64][72];
  int t = threadIdx.x;
  int sc = (t & 15) * 4, erb = t >> 4;
#pragma unroll
  for (int it = 0; it < 4; ++it) {
    int er = erb + it * 16;
    float4 v = *(const float4*)(in + (long long)(e0 + er) * SS + s0 + sc);
    T[sc + 0][er] = f2bf(v.x);
    T[sc + 1][er] = f2bf(v.y);
    T[sc + 2][er] = f2bf(v.z);
    T[sc + 3][er] = f2bf(v.w);
  }
  __syncthreads();
#pragma unroll
  for (int it = 0; it < 2; ++it) {
    int slot = t + it * 256;
    int sr = slot >> 3, ec = (slot & 7) * 8;
    us8 v = *(const us8*)&T[sr][ec];
    *(us8*)(out + (long long)(s0 + sr) * EE + e0 + ec) = v;
  }
}

// ---------------- prep: W f32 -> bf16 ----------------
struct WArgs { const float* w0; const float* w1; const float* w2; const float* w3;
               ushort_t* o0; ushort_t* o1; ushort_t* o2; ushort_t* o3; };

__global__ __launch_bounds__(256) void k_cvt_w(WArgs a) {
  int y = blockIdx.y;
  const float* in = (y == 0) ? a.w0 : (y == 1) ? a.w1 : (y == 2) ? a.w2 : a.w3;
  ushort_t* out = (y == 0) ? a.o0 : (y == 1) ? a.o1 : (y == 2) ? a.o2 : a.o3;
  long long idx = ((long long)blockIdx.x * 256 + threadIdx.x) * 4;
  float4 v = *(const float4*)(in + idx);
  unsigned lo = f2bf(v.x) | ((unsigned)f2bf(v.y) << 16);
  unsigned hi = f2bf(v.z) | ((unsigned)f2bf(v.w) << 16);
  u32x2 pk = {lo, hi};
  *(u32x2*)(out + idx) = pk;
}

// ---------------- unified GEMM: D[m][n] = sum_k A[m][k]*B[n][k]; out[col*LDo+row] ----------------
DEV void stage_tile(const ushort_t* src0, ushort_t* dst0, int w, int lane) {
#pragma unroll
  for (int i = 0; i < 2; ++i) {
    int u = w * 128 + i * 64 + lane;
    int row = u >> 2, part = u & 3;
    gload16(src0 + (long long)row * 1024 + part * 8, dst0 + (w * 128 + i * 64) * 8);
  }
}

template <bool OUTF32, bool BIASROW>
__global__ __launch_bounds__(256) void k_gemm(
    const ushort_t* __restrict__ A, long long sA,
    const ushort_t* __restrict__ Bm, long long sB,
    void* __restrict__ C, long long sC,
    const float* __restrict__ bias, float scale, int LDo) {
  constexpr int K = 1024;
  __shared__ __align__(16) ushort_t As[2][4096];
  __shared__ __align__(16) ushort_t Bs[2][4096];
  int t = threadIdx.x, lane = t & 63, w = t >> 6;
  int lq = lane & 15, g = lane >> 4;
  int m0 = blockIdx.y * 128, n0 = blockIdx.x * 128;
  const ushort_t* Ab = A + (long long)blockIdx.z * sA + (long long)m0 * K;
  const ushort_t* Bb = Bm + (long long)blockIdx.z * sB + (long long)n0 * K;

  f32x4 acc[4][4];
#pragma unroll
  for (int mi = 0; mi < 4; ++mi)
#pragma unroll
    for (int ni = 0; ni < 4; ++ni) acc[mi][ni] = (f32x4){0.f, 0.f, 0.f, 0.f};

  stage_tile(Ab, As[0], w, lane);
  stage_tile(Bb, Bs[0], w, lane);
  __syncthreads();
  int wm = w >> 1, wn = w & 1;
  for (int kt = 0; kt < K / 32; ++kt) {
    int buf = kt & 1;
    if (kt + 1 < K / 32) {
      stage_tile(Ab + (kt + 1) * 32, As[buf ^ 1], w, lane);
      stage_tile(Bb + (kt + 1) * 32, Bs[buf ^ 1], w, lane);
    }
    bf16x8 aF[4], bF[4];
#pragma unroll
    for (int mi = 0; mi < 4; ++mi)
      aF[mi] = *(const bf16x8*)&As[buf][(wm * 64 + mi * 16 + lq) * 32 + g * 8];
#pragma unroll
    for (int ni = 0; ni < 4; ++ni)
      bF[ni] = *(const bf16x8*)&Bs[buf][(wn * 64 + ni * 16 + lq) * 32 + g * 8];
#pragma unroll
    for (int mi = 0; mi < 4; ++mi)
#pragma unroll
      for (int ni = 0; ni < 4; ++ni)
        acc[mi][ni] = __builtin_amdgcn_mfma_f32_16x16x32_bf16(aF[mi], bF[ni], acc[mi][ni], 0, 0, 0);
    __syncthreads();
  }
#pragma unroll
  for (int ni = 0; ni < 4; ++ni) {
    int col = n0 + wn * 64 + ni * 16 + lq;
    float bc = BIASROW ? 0.f : bias[col];
#pragma unroll
    for (int mi = 0; mi < 4; ++mi) {
      int row0 = m0 + wm * 64 + mi * 16 + 4 * g;
      f32x4 v = acc[mi][ni];
#pragma unroll
      for (int r = 0; r < 4; ++r) {
        float bb = BIASROW ? bias[row0 + r] : bc;
        v[r] = (v[r] + bb) * scale;
      }
      if (OUTF32) {
        *(f32x4*)((float*)C + (long long)blockIdx.z * sC + (long long)col * LDo + row0) = v;
      } else {
        unsigned lo = f2bf(v[0]) | ((unsigned)f2bf(v[1]) << 16);
        unsigned hi = f2bf(v[2]) | ((unsigned)f2bf(v[3]) << 16);
        u32x2 pk = {lo, hi};
        *(u32x2*)((ushort_t*)C + (long long)blockIdx.z * sC + (long long)col * LDo + row0) = pk;
      }
    }
  }
}

// ---------------- fused flash attention per (b, h, q-tile 128) ----------------
__global__ __launch_bounds__(256) void k_attn(
    const ushort_t* __restrict__ qpT, const ushort_t* __restrict__ kpT,
    const ushort_t* __restrict__ vp, const float* __restrict__ mask,
    ushort_t* __restrict__ attnT) {
  int t = threadIdx.x, lane = t & 63, w = t >> 6;
  int lq = lane & 15, g = lane >> 4;
  int qt = blockIdx.x, h = blockIdx.y, b = blockIdx.z;
  int q0 = qt * 128;
  const ushort_t* qT = qpT + (long long)b * SS * EE;
  const ushort_t* kT = kpT + (long long)b * SS * EE;
  const ushort_t* vB = vp + (long long)b * EE * SS;
  const float* mk = mask + (long long)b * SS * SS;
  ushort_t* aT = attnT + (long long)b * SS * EE;

  __shared__ __align__(16) ushort_t Qt[8192];     // [chunk2][q128][c32]
  __shared__ __align__(16) ushort_t Kt[2][4096];  // dbuf [chunk2][k64][c32]
  __shared__ __align__(16) ushort_t Pt[4][2048];  // per-wave [chunk2][q32][k32]

  // stage Q tile (once)
#pragma unroll
  for (int i = 0; i < 4; ++i) {
    int u = w * 256 + i * 64 + lane;
    int chunk = u >> 9, rem = u & 511, q = rem >> 2, part = rem & 3;
    gload16(qT + (long long)(q0 + q) * EE + h * 64 + chunk * 32 + part * 8,
            &Qt[(w * 256 + i * 64) * 8]);
  }
  // stage K tile 0
#pragma unroll
  for (int i = 0; i < 2; ++i) {
    int u = w * 128 + i * 64 + lane;
    int chunk = u >> 8, rem = u & 255, k = rem >> 2, part = rem & 3;
    gload16(kT + (long long)k * EE + h * 64 + chunk * 32 + part * 8,
            &Kt[0][(w * 128 + i * 64) * 8]);
  }
  __syncthreads();

  f32x4 accO[4][2];
#pragma unroll
  for (int cf = 0; cf < 4; ++cf)
#pragma unroll
    for (int qf = 0; qf < 2; ++qf) accO[cf][qf] = (f32x4){0.f, 0.f, 0.f, 0.f};
  float mrun[2] = {-3e38f, -3e38f};
  float lrun[2] = {0.f, 0.f};
  int qglob = q0 + w * 32;

  for (int kt = 0; kt < SS / 64; ++kt) {
    int k0 = kt * 64;
    int cur = kt & 1;
    if (kt + 1 < SS / 64) {
#pragma unroll
      for (int i = 0; i < 2; ++i) {
        int u = w * 128 + i * 64 + lane;
        int chunk = u >> 8, rem = u & 255, k = rem >> 2, part = rem & 3;
        gload16(kT + (long long)(k0 + 64 + k) * EE + h * 64 + chunk * 32 + part * 8,
                &Kt[cur ^ 1][(w * 128 + i * 64) * 8]);
      }
    }
    // V fragments direct from global (A-operand of PV)
    bf16x8 vF[4][2];
#pragma unroll
    for (int cf = 0; cf < 4; ++cf)
#pragma unroll
      for (int ch = 0; ch < 2; ++ch)
        vF[cf][ch] = *(const bf16x8*)(vB + (long long)(h * 64 + cf * 16 + lq) * SS + k0 + ch * 32 + 8 * g);
    // mask values (f32, per-lane scalar)
    float mv[4][2][4];
#pragma unroll
    for (int kf = 0; kf < 4; ++kf)
#pragma unroll
      for (int qf = 0; qf < 2; ++qf)
#pragma unroll
        for (int r = 0; r < 4; ++r)
          mv[kf][qf][r] = mk[(long long)(k0 + kf * 16 + 4 * g + r) * SS + (qglob + qf * 16 + lq)];
    // scores: D[k][q] = sum_c K[k][c] * Q[c][q]  (log2 domain via SCALE_Q)
    f32x4 accS[4][2];
#pragma unroll
    for (int kf = 0; kf < 4; ++kf)
#pragma unroll
      for (int qf = 0; qf < 2; ++qf) accS[kf][qf] = (f32x4){0.f, 0.f, 0.f, 0.f};
#pragma unroll
    for (int ch = 0; ch < 2; ++ch) {
      bf16x8 aK[4], bQ[2];
#pragma unroll
      for (int kf = 0; kf < 4; ++kf)
        aK[kf] = *(const bf16x8*)&Kt[cur][ch * 2048 + (kf * 16 + lq) * 32 + g * 8];
#pragma unroll
      for (int qf = 0; qf < 2; ++qf)
        bQ[qf] = *(const bf16x8*)&Qt[ch * 4096 + (w * 32 + qf * 16 + lq) * 32 + g * 8];
#pragma unroll
      for (int kf = 0; kf < 4; ++kf)
#pragma unroll
        for (int qf = 0; qf < 2; ++qf)
          accS[kf][qf] = __builtin_amdgcn_mfma_f32_16x16x32_bf16(aK[kf], bQ[qf], accS[kf][qf], 0, 0, 0);
    }
    // online softmax (exp2 domain), P -> per-wave LDS
#pragma unroll
    for (int qf = 0; qf < 2; ++qf) {
      float sv[4][4];
      float tm = -3e38f;
#pragma unroll
      for (int kf = 0; kf < 4; ++kf)
#pragma unroll
        for (int r = 0; r < 4; ++r) {
          sv[kf][r] = fmaf(mv[kf][qf][r], L2E, accS[kf][qf][r]);
          tm = fmaxf(tm, sv[kf][r]);
        }
      tm = fmaxf(tm, __shfl_xor(tm, 16));
      tm = fmaxf(tm, __shfl_xor(tm, 32));
      float mnew = fmaxf(mrun[qf], tm);
      float corr = __builtin_amdgcn_exp2f(mrun[qf] - mnew);
      mrun[qf] = mnew;
      float p[4][4];
      float ps = 0.f;
#pragma unroll
      for (int kf = 0; kf < 4; ++kf)
#pragma unroll
        for (int r = 0; r < 4; ++r) {
          p[kf][r] = __builtin_amdgcn_exp2f(sv[kf][r] - mnew);
          ps += p[kf][r];
        }
      ps += __shfl_xor(ps, 16);
      ps += __shfl_xor(ps, 32);
      lrun[qf] = lrun[qf] * corr + ps;
#pragma unroll
      for (int cf = 0; cf < 4; ++cf) accO[cf][qf] = accO[cf][qf] * corr;
#pragma unroll
      for (int kf = 0; kf < 4; ++kf) {
        unsigned lo = f2bf(p[kf][0]) | ((unsigned)f2bf(p[kf][1]) << 16);
        unsigned hi = f2bf(p[kf][2]) | ((unsigned)f2bf(p[kf][3]) << 16);
        u32x2 pk = {lo, hi};
        *(u32x2*)&Pt[w][(kf >> 1) * 1024 + (qf * 16 + lq) * 32 + (kf & 1) * 16 + 4 * g] = pk;
      }
    }
    // PV: D[c][q] += V[c][k] * P[k][q]
#pragma unroll
    for (int ch = 0; ch < 2; ++ch) {
      bf16x8 bP[2];
#pragma unroll
      for (int qf = 0; qf < 2; ++qf)
        bP[qf] = *(const bf16x8*)&Pt[w][ch * 1024 + (qf * 16 + lq) * 32 + g * 8];
#pragma unroll
      for (int cf = 0; cf < 4; ++cf)
#pragma unroll
        for (int qf = 0; qf < 2; ++qf)
          accO[cf][qf] = __builtin_amdgcn_mfma_f32_16x16x32_bf16(vF[cf][ch], bP[qf], accO[cf][qf], 0, 0, 0);
    }
    __syncthreads();
  }
  // epilogue: normalize, write attnT[s][c] bf16
#pragma unroll
  for (int qf = 0; qf < 2; ++qf) {
    float inv = 1.f / lrun[qf];
    int s = qglob + qf * 16 + lq;
#pragma unroll
    for (int cf = 0; cf < 4; ++cf) {
      int c0 = h * 64 + cf * 16 + 4 * g;
      f32x4 v = accO[cf][qf];
      unsigned lo = f2bf(v[0] * inv) | ((unsigned)f2bf(v[1] * inv) << 16);
      unsigned hi = f2bf(v[2] * inv) | ((unsigned)f2bf(v[3] * inv) << 16);
      u32x2 pk = {lo, hi};
      *(u32x2*)(aT + (long long)s * EE + c0) = pk;
    }
  }
}

extern "C" void kernel_launch(void* const* d_in, const int* in_sizes, int n_in,
                              void* d_out, int out_size, void* d_ws, size_t ws_size,
                              hipStream_t stream) {
  const float* q = (const float*)d_in[0];
  const float* k = (const float*)d_in[1];
  const float* v = (const float*)d_in[2];
  const float* mask = (const float*)d_in[3];
  const float* Wq = (const float*)d_in[4];
  const float* bq = (const float*)d_in[5];
  const float* Wk = (const float*)d_in[6];
  const float* bk = (const float*)d_in[7];
  const float* Wv = (const float*)d_in[8];
  const float* bv = (const float*)d_in[9];
  const float* Wo = (const float*)d_in[10];
  const float* bo = (const float*)d_in[11];
  float* out = (float*)d_out;

  char* ws = (char*)d_ws;
  const long long MB = 1024LL * 1024LL;
  ushort_t* xqT = (ushort_t*)(ws + 0 * MB);   // [b][s][e] bf16, 8MB
  ushort_t* xkT = (ushort_t*)(ws + 8 * MB);
  ushort_t* xvT = (ushort_t*)(ws + 16 * MB);
  ushort_t* wqB = (ushort_t*)(ws + 24 * MB);  // 2MB each
  ushort_t* wkB = (ushort_t*)(ws + 26 * MB);
  ushort_t* wvB = (ushort_t*)(ws + 28 * MB);
  ushort_t* woB = (ushort_t*)(ws + 30 * MB);
  ushort_t* qpT = (ushort_t*)(ws + 32 * MB);  // [b][s][c] scaled, 8MB
  ushort_t* kpT = (ushort_t*)(ws + 40 * MB);  // [b][s][c]
  ushort_t* vpN = (ushort_t*)(ws + 48 * MB);  // [b][c][s]
  ushort_t* anT = (ushort_t*)(ws + 56 * MB);  // [b][s][c]

  TpArgs tp{q, k, v, xqT, xkT, xvT};
  hipLaunchKernelGGL(k_transpose_cvt, dim3(SS / 64, EE / 64, 6), dim3(256), 0, stream, tp);
  WArgs wa{Wq, Wk, Wv, Wo, wqB, wkB, wvB, woB};
  hipLaunchKernelGGL(k_cvt_w, dim3(1024, 4, 1), dim3(256), 0, stream, wa);

  long long s2 = (long long)SS * EE;
  // qp: D[m=c][n=s] -> qpT[s][c], bias on rows (c), fold dh^-0.5*log2e
  hipLaunchKernelGGL((k_gemm<false, true>), dim3(SS / 128, EE / 128, BB), dim3(256), 0, stream,
                     wqB, 0LL, xqT, s2, (void*)qpT, s2, bq, SCALE_Q, EE);
  // kp: -> kpT[s][c]
  hipLaunchKernelGGL((k_gemm<false, true>), dim3(SS / 128, EE / 128, BB), dim3(256), 0, stream,
                     wkB, 0LL, xkT, s2, (void*)kpT, s2, bk, 1.0f, EE);
  // vp: D[m=s][n=c] -> vp[c][s], bias on cols (c)
  hipLaunchKernelGGL((k_gemm<false, false>), dim3(EE / 128, SS / 128, BB), dim3(256), 0, stream,
                     xvT, s2, wvB, 0LL, (void*)vpN, s2, bv, 1.0f, SS);
  // attention
  hipLaunchKernelGGL(k_attn, dim3(SS / 128, HH, BB), dim3(256), 0, stream,
                     qpT, kpT, vpN, mask, anT);
  // out: D[m=s][n=o] -> out[o][s] f32, bias on cols (o)
  hipLaunchKernelGGL((k_gemm<true, false>), dim3(EE / 128, SS / 128, BB), dim3(256), 0, stream,
                     anT, s2, woB, 0LL, (void*)out, s2, bo, 1.0f, SS);
}